// Round 13
// baseline (173.394 us; speedup 1.0000x reference)
//
#include <hip/hip_runtime.h>
#include <hip/hip_bf16.h>
#include <hip/hip_fp16.h>

#define LQ     12240

typedef _Float16 half8 __attribute__((ext_vector_type(8)));
typedef float floatx4 __attribute__((ext_vector_type(4)));
typedef unsigned int uint;

// ---------------------------------------------------------------------------
// f32 -> f16 elementwise for query + inflat in one dispatch
// ---------------------------------------------------------------------------
__global__ __launch_bounds__(256) void cvt2_f32_f16(
    const float* __restrict__ a, const float* __restrict__ b,
    __half* __restrict__ oa, __half* __restrict__ ob, int n4each) {
  int i = blockIdx.x * 256 + threadIdx.x;
  const float* in = a;
  __half* out = oa;
  if (i >= n4each) { in = b; out = ob; i -= n4each; }
  const float4 v = reinterpret_cast<const float4*>(in)[i];
  const __half2 p0 = __floats2half2_rn(v.x, v.y);
  const __half2 p1 = __floats2half2_rn(v.z, v.w);
  uint2 pk;
  pk.x = *reinterpret_cast<const uint*>(&p0);
  pk.y = *reinterpret_cast<const uint*>(&p1);
  reinterpret_cast<uint2*>(out)[i] = pk;
}

// ---------------------------------------------------------------------------
// All 4 weight transposes in one dispatch: f32 [256][N] -> f16 [N][256]
// attn+off go into the combined wT_ao [1536][256] (attn rows 0-511).
// ---------------------------------------------------------------------------
__global__ __launch_bounds__(256) void transpose_all(
    const float* __restrict__ W_val, const float* __restrict__ W_attn,
    const float* __restrict__ W_off, const float* __restrict__ W_out,
    __half* __restrict__ wT_val, __half* __restrict__ wT_ao,
    __half* __restrict__ wT_out) {
  int b = blockIdx.x;
  const float* in;
  __half* out;
  int N;
  if (b < 64) { in = W_val; out = wT_val; N = 256; }
  else if (b < 192) { b -= 64; in = W_attn; out = wT_ao; N = 512; }
  else if (b < 448) { b -= 192; in = W_off; out = wT_ao + (size_t)512 * 256; N = 1024; }
  else { b -= 448; in = W_out; out = wT_out; N = 256; }
  const int nb = N / 32;
  const int n0 = (b % nb) * 32, k0 = (b / nb) * 32;

  __shared__ float t[32][33];
  const int c = threadIdx.x & 31, r = threadIdx.x >> 5;
#pragma unroll
  for (int i = 0; i < 4; ++i)
    t[r + i * 8][c] = in[(size_t)(k0 + r + i * 8) * N + n0 + c];
  __syncthreads();
#pragma unroll
  for (int i = 0; i < 4; ++i)
    out[(size_t)(n0 + r + i * 8) * 256 + k0 + c] = __float2half(t[c][r + i * 8]);
}

// ---------------------------------------------------------------------------
// MFMA GEMM (r12 base + T14 pipelined staging): C[row*ldc+coff+col] =
// A[M,256] @ Bt[N,256]^T + bias. 128x128 tile, 4 waves, BK=64, reg-staged
// swizzled LDS. Prefetch of K-tile k+1 issues right after the first barrier
// so its latency hides under the MFMA phase (vmcnt vs lgkmcnt independent).
// ---------------------------------------------------------------------------
template <typename TC>
__device__ inline void store_c(TC* C, size_t idx, float v);
template <> __device__ inline void store_c<float>(float* C, size_t idx, float v) { C[idx] = v; }
template <> __device__ inline void store_c<__half>(__half* C, size_t idx, float v) { C[idx] = __float2half(v); }

template <typename TC>
__global__ __launch_bounds__(256) void gemm_mfma(
    const __half* __restrict__ A,    // [M][256]
    const __half* __restrict__ Bt,   // [N][256]
    const float* __restrict__ bias,  // [N]
    TC* __restrict__ C, int M, int N, int ldc, int coff) {
  __shared__ uint4 As_g[128 * 8];
  __shared__ uint4 Bs_g[128 * 8];

  const int tid = threadIdx.x;
  const int bm = blockIdx.y * 128, bn = blockIdx.x * 128;
  const int wid = tid >> 6, lane = tid & 63;
  const int wr = wid >> 1, wn = wid & 1;
  const int l16 = lane & 15, lhi = lane >> 4;

  floatx4 acc[4][4] = {};

  const int srow = tid >> 1;
  const int sg0 = (tid & 1) * 4;
  const bool arow_ok = (bm + srow) < M;
  const __half* Arow = A + (size_t)(arow_ok ? bm + srow : 0) * 256;
  const __half* Brow = Bt + (size_t)(bn + srow) * 256;

  uint4 avr[4], bvr[4];
  // prologue: K-tile 0 into regs
#pragma unroll
  for (int i = 0; i < 4; ++i) {
    const int g = sg0 + i;
    avr[i] = arow_ok ? *reinterpret_cast<const uint4*>(Arow + g * 8)
                     : make_uint4(0, 0, 0, 0);
    bvr[i] = *reinterpret_cast<const uint4*>(Brow + g * 8);
  }

  for (int ks = 0; ks < 4; ++ks) {
    // write current K-tile (regs -> swizzled LDS)
#pragma unroll
    for (int i = 0; i < 4; ++i) {
      const int g = sg0 + i;
      As_g[srow * 8 + (g ^ (srow & 7))] = avr[i];
      Bs_g[srow * 8 + (g ^ (srow & 7))] = bvr[i];
    }
    __syncthreads();

    // issue prefetch of K-tile ks+1 (completes during MFMA phase)
    if (ks < 3) {
      const int k0n = (ks + 1) * 64;
#pragma unroll
      for (int i = 0; i < 4; ++i) {
        const int g = sg0 + i;
        avr[i] = arow_ok ? *reinterpret_cast<const uint4*>(Arow + k0n + g * 8)
                         : make_uint4(0, 0, 0, 0);
        bvr[i] = *reinterpret_cast<const uint4*>(Brow + k0n + g * 8);
      }
    }

#pragma unroll
    for (int kk = 0; kk < 2; ++kk) {
      half8 a[4], b[4];
#pragma unroll
      for (int m = 0; m < 4; ++m) {
        const int row = wr * 64 + m * 16 + l16;
        const int g = kk * 4 + lhi;
        union { uint4 u; half8 h; } cv;
        cv.u = As_g[row * 8 + (g ^ (row & 7))];
        a[m] = cv.h;
      }
#pragma unroll
      for (int n = 0; n < 4; ++n) {
        const int row = wn * 64 + n * 16 + l16;
        const int g = kk * 4 + lhi;
        union { uint4 u; half8 h; } cv;
        cv.u = Bs_g[row * 8 + (g ^ (row & 7))];
        b[n] = cv.h;
      }
#pragma unroll
      for (int m = 0; m < 4; ++m)
#pragma unroll
        for (int n = 0; n < 4; ++n)
          acc[m][n] = __builtin_amdgcn_mfma_f32_16x16x32_f16(a[m], b[n], acc[m][n], 0, 0, 0);
    }
    __syncthreads();
  }

#pragma unroll
  for (int m = 0; m < 4; ++m) {
    const int row0 = bm + wr * 64 + m * 16 + lhi * 4;
#pragma unroll
    for (int n = 0; n < 4; ++n) {
      const int col = bn + wn * 64 + n * 16 + l16;
      const float bv = bias[col];
#pragma unroll
      for (int r = 0; r < 4; ++r) {
        const int row = row0 + r;
        if (row < M)
          store_c<TC>(C, (size_t)row * ldc + coff + col, acc[m][n][r] + bv);
      }
    }
  }
}

// ---------------------------------------------------------------------------
// packed record helper
// ---------------------------------------------------------------------------
__device__ inline uint pack_wr(float w, uint row) {
  const __half hw = __float2half(w);
  return ((uint)__half_as_ushort(hw) << 16) | row;   // row < 12240 < 2^16
}

// ---------------------------------------------------------------------------
// Fused softmax + location + deformable bilinear sampling.
// logits/off read from combined ao buffer, row stride 1536 (r6-proven).
// Phase-2 weight broadcast via v_pk_fma_f16 op_sel:[1,0,0].
// ---------------------------------------------------------------------------
__global__ __launch_bounds__(256, 8) void sample_kernel(
    const __half* __restrict__ value,     // (LQ, 256) f16
    const __half* __restrict__ ao,        // (LQ, 1536) f16: 512 logits | 1024 off
    const float* __restrict__ tempoff,    // (LQ, 4, 4, 2) f32
    const float* __restrict__ refpts,     // (LQ, 4, 2) f32
    __half* __restrict__ msout) {         // (LQ, 256) f16
  const int q0 = blockIdx.x * 2;
  const int tid = threadIdx.x;

  __shared__ __align__(16) uint spk[4096];   // 16 KB packed records
  float* slog = reinterpret_cast<float*>(spk);  // overlay: logits f32[1024]
  __shared__ float sm_m[16], sm_si[16];

  // ---- (a) load logits (2 queries x 512) ----
#pragma unroll
  for (int k = 0; k < 4; ++k) {
    const int s = tid + k * 256;
    slog[s] = __half2float(ao[(size_t)(q0 + (s >> 9)) * 1536 + (s & 511)]);
  }
  __syncthreads();

  // ---- (b) per-(query,head) softmax stats: 16 groups x 16 threads ----
  {
    const int g = tid >> 4;
    const int j = tid & 15;
    const float* e = &slog[g * 64];
    float m = fmaxf(fmaxf(e[j], e[j + 16]), fmaxf(e[j + 32], e[j + 48]));
#pragma unroll
    for (int mask = 8; mask >= 1; mask >>= 1) m = fmaxf(m, __shfl_xor(m, mask));
    float s = __expf(e[j] - m) + __expf(e[j + 16] - m) +
              __expf(e[j + 32] - m) + __expf(e[j + 48] - m);
#pragma unroll
    for (int mask = 8; mask >= 1; mask >>= 1) s += __shfl_xor(s, mask);
    if (j == 0) { sm_m[g] = m; sm_si[g] = 1.0f / s; }
  }
  __syncthreads();

  // ---- (c) per-(sample,corner) records -> registers ----
  const float HWF[4] = {2304.f, 576.f, 144.f, 36.f};
  const float RHW[4] = {1.f / 2304.f, 1.f / 576.f, 1.f / 144.f, 1.f / 36.f};
  const int   S0[4]  = {0, 9216, 11520, 12096};
  const int   HWI[4] = {2304, 576, 144, 36};

  uint4 rec[4];
  int   ridx[4];
  const int h1   = tid & 7;
  const int smid = (tid >> 3) & 7;
  const int shi  = (tid >> 6) & 3;

#pragma unroll
  for (int k = 0; k < 4; ++k) {
    const int qi = k & 1;
    const int s  = smid | (shi << 3) | ((k >> 1) << 5);  // sample id 0..63
    const int i  = h1 * 64 + s;
    const int l  = s >> 4;
    const int f  = (s >> 2) & 3;
    const size_t q = (size_t)(q0 + qi);
    const int g = (qi << 3) | h1;

    const float w = __expf(slog[(qi << 9) + i] - sm_m[g]) * sm_si[g];

    const float2 o  = __half22float2(*reinterpret_cast<const __half2*>(&ao[q * 1536 + 512 + i * 2]));
    const float2 to = *reinterpret_cast<const float2*>(&tempoff[q * 32 + (l * 4 + f) * 2]);
    const float2 rp = *reinterpret_cast<const float2*>(&refpts[q * 8 + l * 2]);

    const float hw = HWF[l];
    const float x = (to.x + o.x * 0.25f + rp.x) * 4.0f - 0.5f;
    const float y = (to.y + o.y * RHW[l] + rp.y) * hw - 0.5f;

    const float x0f = floorf(x), y0f = floorf(y);
    const float fx = x - x0f, fy = y - y0f;
    const int x0 = (int)x0f, y0 = (int)y0f;
    const int hl = HWI[l];

    const bool xv0 = (x0 >= 0) && (x0 < 4);
    const bool xv1 = (x0 >= -1) && (x0 < 3);
    const bool yv0 = (y0 >= 0) && (y0 < hl);
    const bool yv1 = (y0 >= -1) && (y0 < hl - 1);
    const int xc0 = min(max(x0, 0), 3);
    const int xc1 = min(max(x0 + 1, 0), 3);
    const int yc0 = min(max(y0, 0), hl - 1);
    const int yc1 = min(max(y0 + 1, 0), hl - 1);

    const float w00 = (xv0 && yv0) ? w * (1.f - fx) * (1.f - fy) : 0.f;
    const float w01 = (xv1 && yv0) ? w * fx * (1.f - fy) : 0.f;
    const float w10 = (xv0 && yv1) ? w * (1.f - fx) * fy : 0.f;
    const float w11 = (xv1 && yv1) ? w * fx * fy : 0.f;

    const int base = S0[l];
    rec[k] = make_uint4(pack_wr(w00, (uint)(base + yc0 * 4 + xc0)),
                        pack_wr(w01, (uint)(base + yc0 * 4 + xc1)),
                        pack_wr(w10, (uint)(base + yc1 * 4 + xc0)),
                        pack_wr(w11, (uint)(base + yc1 * 4 + xc1)));
    ridx[k] = (qi << 9) | (s << 3) | h1;   // uint4-granule index
  }
  __syncthreads();

  // ---- (d) write records (consecutive granules per wave: conflict-free) ----
  uint4* spk4 = reinterpret_cast<uint4*>(spk);
#pragma unroll
  for (int k = 0; k < 4; ++k) spk4[ridx[k]] = rec[k];
  __syncthreads();

  // ---- phase 2: gather + packed FMA ----
  const int qi = tid >> 7;          // 0..1
  const int h  = (tid >> 4) & 7;    // 0..7
  const int c  = (tid >> 2) & 3;    // corner
  const int d  = tid & 3;           // dim quarter

  const uint* __restrict__ sp = spk + ((qi << 11) | (h << 2) | c);
  const char* __restrict__ vbase = (const char*)value + h * 64 + d * 16;

  float f0 = 0.f, f1 = 0.f, f2 = 0.f, f3 = 0.f;
  float f4 = 0.f, f5 = 0.f, f6 = 0.f, f7 = 0.f;

#pragma unroll
  for (int l = 0; l < 4; ++l) {
    uint a0 = 0u, a1 = 0u, a2 = 0u, a3 = 0u;
#pragma unroll
    for (int t = 0; t < 16; ++t) {
      const uint pk = sp[(l * 16 + t) << 5];           // ds_read_b32 imm offs
      const uint4 v = *reinterpret_cast<const uint4*>(vbase + ((pk & 0xFFFFu) << 9));
      // acc.half = pk.hi(weight) * v.half + acc.half  (op_sel broadcasts hi)
      asm("v_pk_fma_f16 %0, %4, %5, %0 op_sel:[1,0,0]\n\t"
          "v_pk_fma_f16 %1, %4, %6, %1 op_sel:[1,0,0]\n\t"
          "v_pk_fma_f16 %2, %4, %7, %2 op_sel:[1,0,0]\n\t"
          "v_pk_fma_f16 %3, %4, %8, %3 op_sel:[1,0,0]"
          : "+v"(a0), "+v"(a1), "+v"(a2), "+v"(a3)
          : "v"(pk), "v"(v.x), "v"(v.y), "v"(v.z), "v"(v.w));
    }
    const float2 p0 = __half22float2(*reinterpret_cast<const __half2*>(&a0));
    const float2 p1 = __half22float2(*reinterpret_cast<const __half2*>(&a1));
    const float2 p2 = __half22float2(*reinterpret_cast<const __half2*>(&a2));
    const float2 p3 = __half22float2(*reinterpret_cast<const __half2*>(&a3));
    f0 += p0.x; f1 += p0.y; f2 += p1.x; f3 += p1.y;
    f4 += p2.x; f5 += p2.y; f6 += p3.x; f7 += p3.y;
  }

#pragma unroll
  for (int mask = 4; mask <= 8; mask <<= 1) {
    f0 += __shfl_xor(f0, mask); f1 += __shfl_xor(f1, mask);
    f2 += __shfl_xor(f2, mask); f3 += __shfl_xor(f3, mask);
    f4 += __shfl_xor(f4, mask); f5 += __shfl_xor(f5, mask);
    f6 += __shfl_xor(f6, mask); f7 += __shfl_xor(f7, mask);
  }

  if (c == 0) {
    const __half2 o0 = __floats2half2_rn(f0, f1);
    const __half2 o1 = __floats2half2_rn(f2, f3);
    const __half2 o2 = __floats2half2_rn(f4, f5);
    const __half2 o3 = __floats2half2_rn(f6, f7);
    uint4 st;
    st.x = *reinterpret_cast<const uint*>(&o0);
    st.y = *reinterpret_cast<const uint*>(&o1);
    st.z = *reinterpret_cast<const uint*>(&o2);
    st.w = *reinterpret_cast<const uint*>(&o3);
    *reinterpret_cast<uint4*>(&msout[(size_t)(q0 + qi) * 256 + h * 32 + d * 8]) = st;
  }
}

// ---------------------------------------------------------------------------
extern "C" void kernel_launch(void* const* d_in, const int* in_sizes, int n_in,
                              void* d_out, int out_size, void* d_ws, size_t ws_size,
                              hipStream_t stream) {
  const float* query   = (const float*)d_in[0];
  const float* refpts  = (const float*)d_in[1];
  const float* tempoff = (const float*)d_in[2];
  const float* inflat  = (const float*)d_in[3];
  const float* W_off  = (const float*)d_in[6];
  const float* b_off  = (const float*)d_in[7];
  const float* W_attn = (const float*)d_in[8];
  const float* b_attn = (const float*)d_in[9];
  const float* W_val  = (const float*)d_in[10];
  const float* b_val  = (const float*)d_in[11];
  const float* W_out  = (const float*)d_in[12];
  const float* b_out  = (const float*)d_in[13];

  char* ws = (char*)d_ws;
  const size_t szQ = (size_t)LQ * 256 * 2;
  __half* qh     = (__half*)ws;                 ws += szQ;
  __half* ifh    = (__half*)ws;                 ws += szQ;
  __half* wT_val = (__half*)ws;                 ws += (size_t)256 * 256 * 2;
  __half* wT_ao  = (__half*)ws;                 ws += (size_t)1536 * 256 * 2;
  __half* wT_out = (__half*)ws;                 ws += (size_t)256 * 256 * 2;
  __half* val_h  = (__half*)ws;                 ws += szQ;
  __half* ao_h   = (__half*)ws;                 ws += (size_t)LQ * 1536 * 2;
  __half* ms_h   = (__half*)ws;                 ws += szQ;

  const dim3 blk(256);
  const int n4each = LQ * 256 / 4;  // 783360

  cvt2_f32_f16<<<dim3(2 * n4each / 256), blk, 0, stream>>>(query, inflat, qh, ifh, n4each);
  transpose_all<<<dim3(512), blk, 0, stream>>>(W_val, W_attn, W_off, W_out,
                                               wT_val, wT_ao, wT_out);

  const int gm = (LQ + 127) / 128;  // 96
  gemm_mfma<__half><<<dim3(2, gm), blk, 0, stream>>>(ifh, wT_val, b_val, val_h, LQ, 256, 256, 0);
  gemm_mfma<__half><<<dim3(4, gm), blk, 0, stream>>>(qh, wT_ao, b_attn, ao_h, LQ, 512, 1536, 0);
  gemm_mfma<__half><<<dim3(8, gm), blk, 0, stream>>>(qh, wT_ao + (size_t)512 * 256, b_off, ao_h, LQ, 1024, 1536, 512);

  sample_kernel<<<dim3(LQ / 2), blk, 0, stream>>>(val_h, ao_h, tempoff, refpts, ms_h);

  gemm_mfma<float><<<dim3(2, gm), blk, 0, stream>>>(ms_h, wT_out, b_out, (float*)d_out, LQ, 256, 256, 0);
}

// Round 14
// 137.226 us; speedup vs baseline: 1.2636x; 1.2636x over previous
//
#include <hip/hip_runtime.h>
#include <hip/hip_bf16.h>
#include <hip/hip_fp16.h>

#define LQ     12240

typedef _Float16 half8 __attribute__((ext_vector_type(8)));
typedef float floatx4 __attribute__((ext_vector_type(4)));
typedef unsigned int uint;

// ---------------------------------------------------------------------------
// f32 -> f16 elementwise for query + inflat in one dispatch
// ---------------------------------------------------------------------------
__global__ __launch_bounds__(256) void cvt2_f32_f16(
    const float* __restrict__ a, const float* __restrict__ b,
    __half* __restrict__ oa, __half* __restrict__ ob, int n4each) {
  int i = blockIdx.x * 256 + threadIdx.x;
  const float* in = a;
  __half* out = oa;
  if (i >= n4each) { in = b; out = ob; i -= n4each; }
  const float4 v = reinterpret_cast<const float4*>(in)[i];
  const __half2 p0 = __floats2half2_rn(v.x, v.y);
  const __half2 p1 = __floats2half2_rn(v.z, v.w);
  uint2 pk;
  pk.x = *reinterpret_cast<const uint*>(&p0);
  pk.y = *reinterpret_cast<const uint*>(&p1);
  reinterpret_cast<uint2*>(out)[i] = pk;
}

// ---------------------------------------------------------------------------
// All 4 weight transposes in one dispatch: f32 [256][N] -> f16 [N][256]
// attn+off go into the combined wT_ao [1536][256] (attn rows 0-511).
// ---------------------------------------------------------------------------
__global__ __launch_bounds__(256) void transpose_all(
    const float* __restrict__ W_val, const float* __restrict__ W_attn,
    const float* __restrict__ W_off, const float* __restrict__ W_out,
    __half* __restrict__ wT_val, __half* __restrict__ wT_ao,
    __half* __restrict__ wT_out) {
  int b = blockIdx.x;
  const float* in;
  __half* out;
  int N;
  if (b < 64) { in = W_val; out = wT_val; N = 256; }
  else if (b < 192) { b -= 64; in = W_attn; out = wT_ao; N = 512; }
  else if (b < 448) { b -= 192; in = W_off; out = wT_ao + (size_t)512 * 256; N = 1024; }
  else { b -= 448; in = W_out; out = wT_out; N = 256; }
  const int nb = N / 32;
  const int n0 = (b % nb) * 32, k0 = (b / nb) * 32;

  __shared__ float t[32][33];
  const int c = threadIdx.x & 31, r = threadIdx.x >> 5;
#pragma unroll
  for (int i = 0; i < 4; ++i)
    t[r + i * 8][c] = in[(size_t)(k0 + r + i * 8) * N + n0 + c];
  __syncthreads();
#pragma unroll
  for (int i = 0; i < 4; ++i)
    out[(size_t)(n0 + r + i * 8) * 256 + k0 + c] = __float2half(t[c][r + i * 8]);
}

// ---------------------------------------------------------------------------
// MFMA GEMM (r12 proven core): C[M,N] = A[M,256] @ Bt[N,256]^T + bias.
// 128x128 tile, 4 waves, BK=64, register-staged swizzled LDS.
// NEW (T1): XCD-chunked blockIdx remap so blocks sharing an A-row-panel
// land on the same XCD's L2 (nwg % 8 == 0 for all our grids -> bijective).
// ---------------------------------------------------------------------------
template <typename TC>
__device__ inline void store_c(TC* C, size_t idx, float v);
template <> __device__ inline void store_c<float>(float* C, size_t idx, float v) { C[idx] = v; }
template <> __device__ inline void store_c<__half>(__half* C, size_t idx, float v) { C[idx] = __float2half(v); }

template <typename TC>
__global__ __launch_bounds__(256) void gemm_mfma(
    const __half* __restrict__ A,    // [M][256]
    const __half* __restrict__ Bt,   // [N][256]
    const float* __restrict__ bias,  // [N]
    TC* __restrict__ C, int M, int N) {
  __shared__ uint4 As_g[128 * 8];
  __shared__ uint4 Bs_g[128 * 8];

  const int tid = threadIdx.x;

  // XCD-chunked remap: dispatch index d -> orig block id
  const int nwg = gridDim.x * gridDim.y;
  int bid = blockIdx.y * gridDim.x + blockIdx.x;
  bid = (bid & 7) * (nwg >> 3) + (bid >> 3);
  const int bm = (bid / gridDim.x) * 128, bn = (bid % gridDim.x) * 128;

  const int wid = tid >> 6, lane = tid & 63;
  const int wr = wid >> 1, wn = wid & 1;
  const int l16 = lane & 15, lhi = lane >> 4;

  floatx4 acc[4][4] = {};

  const int srow = tid >> 1;
  const int sg0 = (tid & 1) * 4;
  const bool arow_ok = (bm + srow) < M;
  const __half* Arow = A + (size_t)(arow_ok ? bm + srow : 0) * 256;
  const __half* Brow = Bt + (size_t)(bn + srow) * 256;

  for (int ks = 0; ks < 4; ++ks) {
    const int k0 = ks * 64;
#pragma unroll
    for (int i = 0; i < 4; ++i) {
      const int g = sg0 + i;
      uint4 av = make_uint4(0, 0, 0, 0);
      if (arow_ok) av = *reinterpret_cast<const uint4*>(Arow + k0 + g * 8);
      As_g[srow * 8 + (g ^ (srow & 7))] = av;
      Bs_g[srow * 8 + (g ^ (srow & 7))] =
          *reinterpret_cast<const uint4*>(Brow + k0 + g * 8);
    }
    __syncthreads();

#pragma unroll
    for (int kk = 0; kk < 2; ++kk) {
      half8 a[4], b[4];
#pragma unroll
      for (int m = 0; m < 4; ++m) {
        const int row = wr * 64 + m * 16 + l16;
        const int g = kk * 4 + lhi;
        union { uint4 u; half8 h; } cv;
        cv.u = As_g[row * 8 + (g ^ (row & 7))];
        a[m] = cv.h;
      }
#pragma unroll
      for (int n = 0; n < 4; ++n) {
        const int row = wn * 64 + n * 16 + l16;
        const int g = kk * 4 + lhi;
        union { uint4 u; half8 h; } cv;
        cv.u = Bs_g[row * 8 + (g ^ (row & 7))];
        b[n] = cv.h;
      }
#pragma unroll
      for (int m = 0; m < 4; ++m)
#pragma unroll
        for (int n = 0; n < 4; ++n)
          acc[m][n] = __builtin_amdgcn_mfma_f32_16x16x32_f16(a[m], b[n], acc[m][n], 0, 0, 0);
    }
    __syncthreads();
  }

#pragma unroll
  for (int m = 0; m < 4; ++m) {
    const int row0 = bm + wr * 64 + m * 16 + lhi * 4;
#pragma unroll
    for (int n = 0; n < 4; ++n) {
      const int col = bn + wn * 64 + n * 16 + l16;
      const float bv = bias[col];
#pragma unroll
      for (int r = 0; r < 4; ++r) {
        const int row = row0 + r;
        if (row < M) store_c<TC>(C, (size_t)row * N + col, acc[m][n][r] + bv);
      }
    }
  }
}

// ---------------------------------------------------------------------------
// packed record helper
// ---------------------------------------------------------------------------
__device__ inline uint pack_wr(float w, uint row) {
  const __half hw = __float2half(w);
  return ((uint)__half_as_ushort(hw) << 16) | row;   // row < 12240 < 2^16
}

// ---------------------------------------------------------------------------
// Fused softmax + location + deformable bilinear sampling (r12 winner).
// Phase-2 weight broadcast via v_pk_fma_f16 op_sel:[1,0,0].
// ---------------------------------------------------------------------------
__global__ __launch_bounds__(256, 8) void sample_kernel(
    const __half* __restrict__ value,     // (LQ, 256) f16
    const __half* __restrict__ logits,    // (LQ, 512) f16
    const __half* __restrict__ off,       // (LQ, 1024) f16
    const float* __restrict__ tempoff,    // (LQ, 4, 4, 2) f32
    const float* __restrict__ refpts,     // (LQ, 4, 2) f32
    __half* __restrict__ msout) {         // (LQ, 256) f16
  const int q0 = blockIdx.x * 2;
  const int tid = threadIdx.x;

  __shared__ __align__(16) uint spk[4096];   // 16 KB packed records
  float* slog = reinterpret_cast<float*>(spk);  // overlay: logits f32[1024]
  __shared__ float sm_m[16], sm_si[16];

  // ---- (a) load logits (2 queries x 512) ----
#pragma unroll
  for (int k = 0; k < 4; ++k) {
    const int s = tid + k * 256;
    slog[s] = __half2float(logits[(size_t)(q0 + (s >> 9)) * 512 + (s & 511)]);
  }
  __syncthreads();

  // ---- (b) per-(query,head) softmax stats: 16 groups x 16 threads ----
  {
    const int g = tid >> 4;
    const int j = tid & 15;
    const float* e = &slog[g * 64];
    float m = fmaxf(fmaxf(e[j], e[j + 16]), fmaxf(e[j + 32], e[j + 48]));
#pragma unroll
    for (int mask = 8; mask >= 1; mask >>= 1) m = fmaxf(m, __shfl_xor(m, mask));
    float s = __expf(e[j] - m) + __expf(e[j + 16] - m) +
              __expf(e[j + 32] - m) + __expf(e[j + 48] - m);
#pragma unroll
    for (int mask = 8; mask >= 1; mask >>= 1) s += __shfl_xor(s, mask);
    if (j == 0) { sm_m[g] = m; sm_si[g] = 1.0f / s; }
  }
  __syncthreads();

  // ---- (c) per-(sample,corner) records -> registers ----
  const float HWF[4] = {2304.f, 576.f, 144.f, 36.f};
  const float RHW[4] = {1.f / 2304.f, 1.f / 576.f, 1.f / 144.f, 1.f / 36.f};
  const int   S0[4]  = {0, 9216, 11520, 12096};
  const int   HWI[4] = {2304, 576, 144, 36};

  uint4 rec[4];
  int   ridx[4];
  const int h1   = tid & 7;
  const int smid = (tid >> 3) & 7;
  const int shi  = (tid >> 6) & 3;

#pragma unroll
  for (int k = 0; k < 4; ++k) {
    const int qi = k & 1;
    const int s  = smid | (shi << 3) | ((k >> 1) << 5);  // sample id 0..63
    const int i  = h1 * 64 + s;
    const int l  = s >> 4;
    const int f  = (s >> 2) & 3;
    const size_t q = (size_t)(q0 + qi);
    const int g = (qi << 3) | h1;

    const float w = __expf(slog[(qi << 9) + i] - sm_m[g]) * sm_si[g];

    const float2 o  = __half22float2(*reinterpret_cast<const __half2*>(&off[q * 1024 + i * 2]));
    const float2 to = *reinterpret_cast<const float2*>(&tempoff[q * 32 + (l * 4 + f) * 2]);
    const float2 rp = *reinterpret_cast<const float2*>(&refpts[q * 8 + l * 2]);

    const float hw = HWF[l];
    const float x = (to.x + o.x * 0.25f + rp.x) * 4.0f - 0.5f;
    const float y = (to.y + o.y * RHW[l] + rp.y) * hw - 0.5f;

    const float x0f = floorf(x), y0f = floorf(y);
    const float fx = x - x0f, fy = y - y0f;
    const int x0 = (int)x0f, y0 = (int)y0f;
    const int hl = HWI[l];

    const bool xv0 = (x0 >= 0) && (x0 < 4);
    const bool xv1 = (x0 >= -1) && (x0 < 3);
    const bool yv0 = (y0 >= 0) && (y0 < hl);
    const bool yv1 = (y0 >= -1) && (y0 < hl - 1);
    const int xc0 = min(max(x0, 0), 3);
    const int xc1 = min(max(x0 + 1, 0), 3);
    const int yc0 = min(max(y0, 0), hl - 1);
    const int yc1 = min(max(y0 + 1, 0), hl - 1);

    const float w00 = (xv0 && yv0) ? w * (1.f - fx) * (1.f - fy) : 0.f;
    const float w01 = (xv1 && yv0) ? w * fx * (1.f - fy) : 0.f;
    const float w10 = (xv0 && yv1) ? w * (1.f - fx) * fy : 0.f;
    const float w11 = (xv1 && yv1) ? w * fx * fy : 0.f;

    const int base = S0[l];
    rec[k] = make_uint4(pack_wr(w00, (uint)(base + yc0 * 4 + xc0)),
                        pack_wr(w01, (uint)(base + yc0 * 4 + xc1)),
                        pack_wr(w10, (uint)(base + yc1 * 4 + xc0)),
                        pack_wr(w11, (uint)(base + yc1 * 4 + xc1)));
    ridx[k] = (qi << 9) | (s << 3) | h1;   // uint4-granule index
  }
  __syncthreads();

  // ---- (d) write records (consecutive granules per wave: conflict-free) ----
  uint4* spk4 = reinterpret_cast<uint4*>(spk);
#pragma unroll
  for (int k = 0; k < 4; ++k) spk4[ridx[k]] = rec[k];
  __syncthreads();

  // ---- phase 2: gather + packed FMA ----
  const int qi = tid >> 7;          // 0..1
  const int h  = (tid >> 4) & 7;    // 0..7
  const int c  = (tid >> 2) & 3;    // corner
  const int d  = tid & 3;           // dim quarter

  const uint* __restrict__ sp = spk + ((qi << 11) | (h << 2) | c);
  const char* __restrict__ vbase = (const char*)value + h * 64 + d * 16;

  float f0 = 0.f, f1 = 0.f, f2 = 0.f, f3 = 0.f;
  float f4 = 0.f, f5 = 0.f, f6 = 0.f, f7 = 0.f;

#pragma unroll
  for (int l = 0; l < 4; ++l) {
    uint a0 = 0u, a1 = 0u, a2 = 0u, a3 = 0u;
#pragma unroll
    for (int t = 0; t < 16; ++t) {
      const uint pk = sp[(l * 16 + t) << 5];           // ds_read_b32 imm offs
      const uint4 v = *reinterpret_cast<const uint4*>(vbase + ((pk & 0xFFFFu) << 9));
      // acc.half = pk.hi(weight) * v.half + acc.half  (op_sel broadcasts hi)
      asm("v_pk_fma_f16 %0, %4, %5, %0 op_sel:[1,0,0]\n\t"
          "v_pk_fma_f16 %1, %4, %6, %1 op_sel:[1,0,0]\n\t"
          "v_pk_fma_f16 %2, %4, %7, %2 op_sel:[1,0,0]\n\t"
          "v_pk_fma_f16 %3, %4, %8, %3 op_sel:[1,0,0]"
          : "+v"(a0), "+v"(a1), "+v"(a2), "+v"(a3)
          : "v"(pk), "v"(v.x), "v"(v.y), "v"(v.z), "v"(v.w));
    }
    const float2 p0 = __half22float2(*reinterpret_cast<const __half2*>(&a0));
    const float2 p1 = __half22float2(*reinterpret_cast<const __half2*>(&a1));
    const float2 p2 = __half22float2(*reinterpret_cast<const __half2*>(&a2));
    const float2 p3 = __half22float2(*reinterpret_cast<const __half2*>(&a3));
    f0 += p0.x; f1 += p0.y; f2 += p1.x; f3 += p1.y;
    f4 += p2.x; f5 += p2.y; f6 += p3.x; f7 += p3.y;
  }

#pragma unroll
  for (int mask = 4; mask <= 8; mask <<= 1) {
    f0 += __shfl_xor(f0, mask); f1 += __shfl_xor(f1, mask);
    f2 += __shfl_xor(f2, mask); f3 += __shfl_xor(f3, mask);
    f4 += __shfl_xor(f4, mask); f5 += __shfl_xor(f5, mask);
    f6 += __shfl_xor(f6, mask); f7 += __shfl_xor(f7, mask);
  }

  if (c == 0) {
    const __half2 o0 = __floats2half2_rn(f0, f1);
    const __half2 o1 = __floats2half2_rn(f2, f3);
    const __half2 o2 = __floats2half2_rn(f4, f5);
    const __half2 o3 = __floats2half2_rn(f6, f7);
    uint4 st;
    st.x = *reinterpret_cast<const uint*>(&o0);
    st.y = *reinterpret_cast<const uint*>(&o1);
    st.z = *reinterpret_cast<const uint*>(&o2);
    st.w = *reinterpret_cast<const uint*>(&o3);
    *reinterpret_cast<uint4*>(&msout[(size_t)(q0 + qi) * 256 + h * 32 + d * 8]) = st;
  }
}

// ---------------------------------------------------------------------------
extern "C" void kernel_launch(void* const* d_in, const int* in_sizes, int n_in,
                              void* d_out, int out_size, void* d_ws, size_t ws_size,
                              hipStream_t stream) {
  const float* query   = (const float*)d_in[0];
  const float* refpts  = (const float*)d_in[1];
  const float* tempoff = (const float*)d_in[2];
  const float* inflat  = (const float*)d_in[3];
  const float* W_off  = (const float*)d_in[6];
  const float* b_off  = (const float*)d_in[7];
  const float* W_attn = (const float*)d_in[8];
  const float* b_attn = (const float*)d_in[9];
  const float* W_val  = (const float*)d_in[10];
  const float* b_val  = (const float*)d_in[11];
  const float* W_out  = (const float*)d_in[12];
  const float* b_out  = (const float*)d_in[13];

  char* ws = (char*)d_ws;
  const size_t szQ = (size_t)LQ * 256 * 2;
  __half* qh     = (__half*)ws;                 ws += szQ;
  __half* ifh    = (__half*)ws;                 ws += szQ;
  __half* wT_val = (__half*)ws;                 ws += (size_t)256 * 256 * 2;
  __half* wT_ao  = (__half*)ws;                 ws += (size_t)1536 * 256 * 2;
  __half* wT_out = (__half*)ws;                 ws += (size_t)256 * 256 * 2;
  __half* val_h  = (__half*)ws;                 ws += szQ;
  __half* attn_h = (__half*)ws;                 ws += (size_t)LQ * 512 * 2;
  __half* off_h  = (__half*)ws;                 ws += (size_t)LQ * 1024 * 2;
  __half* ms_h   = (__half*)ws;                 ws += szQ;

  const dim3 blk(256);
  const int n4each = LQ * 256 / 4;  // 783360

  cvt2_f32_f16<<<dim3(2 * n4each / 256), blk, 0, stream>>>(query, inflat, qh, ifh, n4each);
  transpose_all<<<dim3(512), blk, 0, stream>>>(W_val, W_attn, W_off, W_out,
                                               wT_val, wT_ao, wT_out);

  const int gm = (LQ + 127) / 128;  // 96
  gemm_mfma<__half><<<dim3(2, gm), blk, 0, stream>>>(ifh, wT_val, b_val, val_h, LQ, 256);
  gemm_mfma<__half><<<dim3(4, gm), blk, 0, stream>>>(qh, wT_ao, b_attn, attn_h, LQ, 512);
  gemm_mfma<__half><<<dim3(8, gm), blk, 0, stream>>>(qh, wT_ao + (size_t)512 * 256, b_off, off_h, LQ, 1024);

  sample_kernel<<<dim3(LQ / 2), blk, 0, stream>>>(val_h, attn_h, off_h, tempoff, refpts, ms_h);

  gemm_mfma<float><<<dim3(2, gm), blk, 0, stream>>>(ms_h, wT_out, b_out, (float*)d_out, LQ, 256);
}

// Round 15
// 136.485 us; speedup vs baseline: 1.2704x; 1.0054x over previous
//
#include <hip/hip_runtime.h>
#include <hip/hip_bf16.h>
#include <hip/hip_fp16.h>

#define LQ     12240

typedef _Float16 half8 __attribute__((ext_vector_type(8)));
typedef float floatx4 __attribute__((ext_vector_type(4)));
typedef unsigned int uint;

// ---------------------------------------------------------------------------
// f32 -> f16 elementwise for query + inflat in one dispatch
// ---------------------------------------------------------------------------
__global__ __launch_bounds__(256) void cvt2_f32_f16(
    const float* __restrict__ a, const float* __restrict__ b,
    __half* __restrict__ oa, __half* __restrict__ ob, int n4each) {
  int i = blockIdx.x * 256 + threadIdx.x;
  const float* in = a;
  __half* out = oa;
  if (i >= n4each) { in = b; out = ob; i -= n4each; }
  const float4 v = reinterpret_cast<const float4*>(in)[i];
  const __half2 p0 = __floats2half2_rn(v.x, v.y);
  const __half2 p1 = __floats2half2_rn(v.z, v.w);
  uint2 pk;
  pk.x = *reinterpret_cast<const uint*>(&p0);
  pk.y = *reinterpret_cast<const uint*>(&p1);
  reinterpret_cast<uint2*>(out)[i] = pk;
}

// ---------------------------------------------------------------------------
// All 4 weight transposes in one dispatch: f32 [256][N] -> f16 [N][256]
// attn+off go into the combined wT_ao [1536][256] (attn rows 0-511).
// ---------------------------------------------------------------------------
__global__ __launch_bounds__(256) void transpose_all(
    const float* __restrict__ W_val, const float* __restrict__ W_attn,
    const float* __restrict__ W_off, const float* __restrict__ W_out,
    __half* __restrict__ wT_val, __half* __restrict__ wT_ao,
    __half* __restrict__ wT_out) {
  int b = blockIdx.x;
  const float* in;
  __half* out;
  int N;
  if (b < 64) { in = W_val; out = wT_val; N = 256; }
  else if (b < 192) { b -= 64; in = W_attn; out = wT_ao; N = 512; }
  else if (b < 448) { b -= 192; in = W_off; out = wT_ao + (size_t)512 * 256; N = 1024; }
  else { b -= 448; in = W_out; out = wT_out; N = 256; }
  const int nb = N / 32;
  const int n0 = (b % nb) * 32, k0 = (b / nb) * 32;

  __shared__ float t[32][33];
  const int c = threadIdx.x & 31, r = threadIdx.x >> 5;
#pragma unroll
  for (int i = 0; i < 4; ++i)
    t[r + i * 8][c] = in[(size_t)(k0 + r + i * 8) * N + n0 + c];
  __syncthreads();
#pragma unroll
  for (int i = 0; i < 4; ++i)
    out[(size_t)(n0 + r + i * 8) * 256 + k0 + c] = __float2half(t[c][r + i * 8]);
}

// ---------------------------------------------------------------------------
// MFMA GEMM (r12 proven core + r14 XCD remap): C = A[M,256] @ Bt[N,256]^T
// + bias. 128x128 tile, 4 waves, BK=64, register-staged swizzled LDS.
// TRANS=true writes the head-major layout val_t[h][row][32] used by the
// sampler (idx = (col>>5)*M32 + row*32 + (col&31)).
// ---------------------------------------------------------------------------
template <typename TC>
__device__ inline void store_c(TC* C, size_t idx, float v);
template <> __device__ inline void store_c<float>(float* C, size_t idx, float v) { C[idx] = v; }
template <> __device__ inline void store_c<__half>(__half* C, size_t idx, float v) { C[idx] = __float2half(v); }

template <typename TC, bool TRANS>
__global__ __launch_bounds__(256) void gemm_mfma(
    const __half* __restrict__ A,    // [M][256]
    const __half* __restrict__ Bt,   // [N][256]
    const float* __restrict__ bias,  // [N]
    TC* __restrict__ C, int M, int N) {
  __shared__ uint4 As_g[128 * 8];
  __shared__ uint4 Bs_g[128 * 8];

  const int tid = threadIdx.x;

  // XCD-chunked remap: dispatch index -> orig block id (nwg % 8 == 0)
  const int nwg = gridDim.x * gridDim.y;
  int bid = blockIdx.y * gridDim.x + blockIdx.x;
  bid = (bid & 7) * (nwg >> 3) + (bid >> 3);
  const int bm = (bid / gridDim.x) * 128, bn = (bid % gridDim.x) * 128;

  const int wid = tid >> 6, lane = tid & 63;
  const int wr = wid >> 1, wn = wid & 1;
  const int l16 = lane & 15, lhi = lane >> 4;

  floatx4 acc[4][4] = {};

  const int srow = tid >> 1;
  const int sg0 = (tid & 1) * 4;
  const bool arow_ok = (bm + srow) < M;
  const __half* Arow = A + (size_t)(arow_ok ? bm + srow : 0) * 256;
  const __half* Brow = Bt + (size_t)(bn + srow) * 256;

  for (int ks = 0; ks < 4; ++ks) {
    const int k0 = ks * 64;
#pragma unroll
    for (int i = 0; i < 4; ++i) {
      const int g = sg0 + i;
      uint4 av = make_uint4(0, 0, 0, 0);
      if (arow_ok) av = *reinterpret_cast<const uint4*>(Arow + k0 + g * 8);
      As_g[srow * 8 + (g ^ (srow & 7))] = av;
      Bs_g[srow * 8 + (g ^ (srow & 7))] =
          *reinterpret_cast<const uint4*>(Brow + k0 + g * 8);
    }
    __syncthreads();

#pragma unroll
    for (int kk = 0; kk < 2; ++kk) {
      half8 a[4], b[4];
#pragma unroll
      for (int m = 0; m < 4; ++m) {
        const int row = wr * 64 + m * 16 + l16;
        const int g = kk * 4 + lhi;
        union { uint4 u; half8 h; } cv;
        cv.u = As_g[row * 8 + (g ^ (row & 7))];
        a[m] = cv.h;
      }
#pragma unroll
      for (int n = 0; n < 4; ++n) {
        const int row = wn * 64 + n * 16 + l16;
        const int g = kk * 4 + lhi;
        union { uint4 u; half8 h; } cv;
        cv.u = Bs_g[row * 8 + (g ^ (row & 7))];
        b[n] = cv.h;
      }
#pragma unroll
      for (int m = 0; m < 4; ++m)
#pragma unroll
        for (int n = 0; n < 4; ++n)
          acc[m][n] = __builtin_amdgcn_mfma_f32_16x16x32_f16(a[m], b[n], acc[m][n], 0, 0, 0);
    }
    __syncthreads();
  }

#pragma unroll
  for (int m = 0; m < 4; ++m) {
    const int row0 = bm + wr * 64 + m * 16 + lhi * 4;
#pragma unroll
    for (int n = 0; n < 4; ++n) {
      const int col = bn + wn * 64 + n * 16 + l16;
      const float bv = bias[col];
#pragma unroll
      for (int r = 0; r < 4; ++r) {
        const int row = row0 + r;
        if (row < M) {
          size_t idx;
          if (TRANS) idx = (size_t)(col >> 5) * ((size_t)M * 32) + (size_t)row * 32 + (col & 31);
          else       idx = (size_t)row * N + col;
          store_c<TC>(C, idx, acc[m][n][r] + bv);
        }
      }
    }
  }
}

// ---------------------------------------------------------------------------
// packed record helper
// ---------------------------------------------------------------------------
__device__ inline uint pack_wr(float w, uint row) {
  const __half hw = __float2half(w);
  return ((uint)__half_as_ushort(hw) << 16) | row;   // row < 12240 < 2^16
}

// ---------------------------------------------------------------------------
// Fused softmax + location + deformable bilinear sampling (r12/r14 winner).
// value is now head-major val_t[h][row][32] -> the two x-corners of a sample
// are 64B apart (same 128B line), y-corners 256B apart: ~2x fewer cache-line
// touches on the gather. Phase-2 weight broadcast via v_pk_fma op_sel.
// ---------------------------------------------------------------------------
__global__ __launch_bounds__(256, 8) void sample_kernel(
    const __half* __restrict__ value,     // val_t [8][LQ][32] f16
    const __half* __restrict__ logits,    // (LQ, 512) f16
    const __half* __restrict__ off,       // (LQ, 1024) f16
    const float* __restrict__ tempoff,    // (LQ, 4, 4, 2) f32
    const float* __restrict__ refpts,     // (LQ, 4, 2) f32
    __half* __restrict__ msout) {         // (LQ, 256) f16
  const int q0 = blockIdx.x * 2;
  const int tid = threadIdx.x;

  __shared__ __align__(16) uint spk[4096];   // 16 KB packed records
  float* slog = reinterpret_cast<float*>(spk);  // overlay: logits f32[1024]
  __shared__ float sm_m[16], sm_si[16];

  // ---- (a) load logits (2 queries x 512) ----
#pragma unroll
  for (int k = 0; k < 4; ++k) {
    const int s = tid + k * 256;
    slog[s] = __half2float(logits[(size_t)(q0 + (s >> 9)) * 512 + (s & 511)]);
  }
  __syncthreads();

  // ---- (b) per-(query,head) softmax stats: 16 groups x 16 threads ----
  {
    const int g = tid >> 4;
    const int j = tid & 15;
    const float* e = &slog[g * 64];
    float m = fmaxf(fmaxf(e[j], e[j + 16]), fmaxf(e[j + 32], e[j + 48]));
#pragma unroll
    for (int mask = 8; mask >= 1; mask >>= 1) m = fmaxf(m, __shfl_xor(m, mask));
    float s = __expf(e[j] - m) + __expf(e[j + 16] - m) +
              __expf(e[j + 32] - m) + __expf(e[j + 48] - m);
#pragma unroll
    for (int mask = 8; mask >= 1; mask >>= 1) s += __shfl_xor(s, mask);
    if (j == 0) { sm_m[g] = m; sm_si[g] = 1.0f / s; }
  }
  __syncthreads();

  // ---- (c) per-(sample,corner) records -> registers ----
  const float HWF[4] = {2304.f, 576.f, 144.f, 36.f};
  const float RHW[4] = {1.f / 2304.f, 1.f / 576.f, 1.f / 144.f, 1.f / 36.f};
  const int   S0[4]  = {0, 9216, 11520, 12096};
  const int   HWI[4] = {2304, 576, 144, 36};

  uint4 rec[4];
  int   ridx[4];
  const int h1   = tid & 7;
  const int smid = (tid >> 3) & 7;
  const int shi  = (tid >> 6) & 3;

#pragma unroll
  for (int k = 0; k < 4; ++k) {
    const int qi = k & 1;
    const int s  = smid | (shi << 3) | ((k >> 1) << 5);  // sample id 0..63
    const int i  = h1 * 64 + s;
    const int l  = s >> 4;
    const int f  = (s >> 2) & 3;
    const size_t q = (size_t)(q0 + qi);
    const int g = (qi << 3) | h1;

    const float w = __expf(slog[(qi << 9) + i] - sm_m[g]) * sm_si[g];

    const float2 o  = __half22float2(*reinterpret_cast<const __half2*>(&off[q * 1024 + i * 2]));
    const float2 to = *reinterpret_cast<const float2*>(&tempoff[q * 32 + (l * 4 + f) * 2]);
    const float2 rp = *reinterpret_cast<const float2*>(&refpts[q * 8 + l * 2]);

    const float hw = HWF[l];
    const float x = (to.x + o.x * 0.25f + rp.x) * 4.0f - 0.5f;
    const float y = (to.y + o.y * RHW[l] + rp.y) * hw - 0.5f;

    const float x0f = floorf(x), y0f = floorf(y);
    const float fx = x - x0f, fy = y - y0f;
    const int x0 = (int)x0f, y0 = (int)y0f;
    const int hl = HWI[l];

    const bool xv0 = (x0 >= 0) && (x0 < 4);
    const bool xv1 = (x0 >= -1) && (x0 < 3);
    const bool yv0 = (y0 >= 0) && (y0 < hl);
    const bool yv1 = (y0 >= -1) && (y0 < hl - 1);
    const int xc0 = min(max(x0, 0), 3);
    const int xc1 = min(max(x0 + 1, 0), 3);
    const int yc0 = min(max(y0, 0), hl - 1);
    const int yc1 = min(max(y0 + 1, 0), hl - 1);

    const float w00 = (xv0 && yv0) ? w * (1.f - fx) * (1.f - fy) : 0.f;
    const float w01 = (xv1 && yv0) ? w * fx * (1.f - fy) : 0.f;
    const float w10 = (xv0 && yv1) ? w * (1.f - fx) * fy : 0.f;
    const float w11 = (xv1 && yv1) ? w * fx * fy : 0.f;

    const int base = S0[l];
    rec[k] = make_uint4(pack_wr(w00, (uint)(base + yc0 * 4 + xc0)),
                        pack_wr(w01, (uint)(base + yc0 * 4 + xc1)),
                        pack_wr(w10, (uint)(base + yc1 * 4 + xc0)),
                        pack_wr(w11, (uint)(base + yc1 * 4 + xc1)));
    ridx[k] = (qi << 9) | (s << 3) | h1;   // uint4-granule index
  }
  __syncthreads();

  // ---- (d) write records (consecutive granules per wave: conflict-free) ----
  uint4* spk4 = reinterpret_cast<uint4*>(spk);
#pragma unroll
  for (int k = 0; k < 4; ++k) spk4[ridx[k]] = rec[k];
  __syncthreads();

  // ---- phase 2: gather + packed FMA ----
  const int qi = tid >> 7;          // 0..1
  const int h  = (tid >> 4) & 7;    // 0..7
  const int c  = (tid >> 2) & 3;    // corner
  const int d  = tid & 3;           // dim quarter

  const uint* __restrict__ sp = spk + ((qi << 11) | (h << 2) | c);
  const char* __restrict__ vbase =
      (const char*)value + (size_t)h * LQ * 64 + d * 16;

  float f0 = 0.f, f1 = 0.f, f2 = 0.f, f3 = 0.f;
  float f4 = 0.f, f5 = 0.f, f6 = 0.f, f7 = 0.f;

#pragma unroll
  for (int l = 0; l < 4; ++l) {
    uint a0 = 0u, a1 = 0u, a2 = 0u, a3 = 0u;
#pragma unroll
    for (int t = 0; t < 16; ++t) {
      const uint pk = sp[(l * 16 + t) << 5];           // ds_read_b32 imm offs
      const uint4 v = *reinterpret_cast<const uint4*>(vbase + ((pk & 0xFFFFu) << 6));
      // acc.half = pk.hi(weight) * v.half + acc.half  (op_sel broadcasts hi)
      asm("v_pk_fma_f16 %0, %4, %5, %0 op_sel:[1,0,0]\n\t"
          "v_pk_fma_f16 %1, %4, %6, %1 op_sel:[1,0,0]\n\t"
          "v_pk_fma_f16 %2, %4, %7, %2 op_sel:[1,0,0]\n\t"
          "v_pk_fma_f16 %3, %4, %8, %3 op_sel:[1,0,0]"
          : "+v"(a0), "+v"(a1), "+v"(a2), "+v"(a3)
          : "v"(pk), "v"(v.x), "v"(v.y), "v"(v.z), "v"(v.w));
    }
    const float2 p0 = __half22float2(*reinterpret_cast<const __half2*>(&a0));
    const float2 p1 = __half22float2(*reinterpret_cast<const __half2*>(&a1));
    const float2 p2 = __half22float2(*reinterpret_cast<const __half2*>(&a2));
    const float2 p3 = __half22float2(*reinterpret_cast<const __half2*>(&a3));
    f0 += p0.x; f1 += p0.y; f2 += p1.x; f3 += p1.y;
    f4 += p2.x; f5 += p2.y; f6 += p3.x; f7 += p3.y;
  }

#pragma unroll
  for (int mask = 4; mask <= 8; mask <<= 1) {
    f0 += __shfl_xor(f0, mask); f1 += __shfl_xor(f1, mask);
    f2 += __shfl_xor(f2, mask); f3 += __shfl_xor(f3, mask);
    f4 += __shfl_xor(f4, mask); f5 += __shfl_xor(f5, mask);
    f6 += __shfl_xor(f6, mask); f7 += __shfl_xor(f7, mask);
  }

  if (c == 0) {
    const __half2 o0 = __floats2half2_rn(f0, f1);
    const __half2 o1 = __floats2half2_rn(f2, f3);
    const __half2 o2 = __floats2half2_rn(f4, f5);
    const __half2 o3 = __floats2half2_rn(f6, f7);
    uint4 st;
    st.x = *reinterpret_cast<const uint*>(&o0);
    st.y = *reinterpret_cast<const uint*>(&o1);
    st.z = *reinterpret_cast<const uint*>(&o2);
    st.w = *reinterpret_cast<const uint*>(&o3);
    *reinterpret_cast<uint4*>(&msout[(size_t)(q0 + qi) * 256 + h * 32 + d * 8]) = st;
  }
}

// ---------------------------------------------------------------------------
extern "C" void kernel_launch(void* const* d_in, const int* in_sizes, int n_in,
                              void* d_out, int out_size, void* d_ws, size_t ws_size,
                              hipStream_t stream) {
  const float* query   = (const float*)d_in[0];
  const float* refpts  = (const float*)d_in[1];
  const float* tempoff = (const float*)d_in[2];
  const float* inflat  = (const float*)d_in[3];
  const float* W_off  = (const float*)d_in[6];
  const float* b_off  = (const float*)d_in[7];
  const float* W_attn = (const float*)d_in[8];
  const float* b_attn = (const float*)d_in[9];
  const float* W_val  = (const float*)d_in[10];
  const float* b_val  = (const float*)d_in[11];
  const float* W_out  = (const float*)d_in[12];
  const float* b_out  = (const float*)d_in[13];

  char* ws = (char*)d_ws;
  const size_t szQ = (size_t)LQ * 256 * 2;
  __half* qh     = (__half*)ws;                 ws += szQ;
  __half* ifh    = (__half*)ws;                 ws += szQ;
  __half* wT_val = (__half*)ws;                 ws += (size_t)256 * 256 * 2;
  __half* wT_ao  = (__half*)ws;                 ws += (size_t)1536 * 256 * 2;
  __half* wT_out = (__half*)ws;                 ws += (size_t)256 * 256 * 2;
  __half* val_t  = (__half*)ws;                 ws += szQ;
  __half* attn_h = (__half*)ws;                 ws += (size_t)LQ * 512 * 2;
  __half* off_h  = (__half*)ws;                 ws += (size_t)LQ * 1024 * 2;
  __half* ms_h   = (__half*)ws;                 ws += szQ;

  const dim3 blk(256);
  const int n4each = LQ * 256 / 4;  // 783360

  cvt2_f32_f16<<<dim3(2 * n4each / 256), blk, 0, stream>>>(query, inflat, qh, ifh, n4each);
  transpose_all<<<dim3(512), blk, 0, stream>>>(W_val, W_attn, W_off, W_out,
                                               wT_val, wT_ao, wT_out);

  const int gm = (LQ + 127) / 128;  // 96
  gemm_mfma<__half, true><<<dim3(2, gm), blk, 0, stream>>>(ifh, wT_val, b_val, val_t, LQ, 256);
  gemm_mfma<__half, false><<<dim3(4, gm), blk, 0, stream>>>(qh, wT_ao, b_attn, attn_h, LQ, 512);
  gemm_mfma<__half, false><<<dim3(8, gm), blk, 0, stream>>>(qh, wT_ao + (size_t)512 * 256, b_off, off_h, LQ, 1024);

  sample_kernel<<<dim3(LQ / 2), blk, 0, stream>>>(val_t, attn_h, off_h, tempoff, refpts, ms_h);

  gemm_mfma<float, false><<<dim3(2, gm), blk, 0, stream>>>(ms_h, wT_out, b_out, (float*)d_out, LQ, 256);
}

// Round 16
// 124.629 us; speedup vs baseline: 1.3913x; 1.0951x over previous
//
#include <hip/hip_runtime.h>
#include <hip/hip_bf16.h>
#include <hip/hip_fp16.h>

#define LQ     12240

typedef _Float16 half8 __attribute__((ext_vector_type(8)));
typedef float floatx4 __attribute__((ext_vector_type(4)));
typedef unsigned int uint;

// ---------------------------------------------------------------------------
// Merged prep: blocks 0-511 = weight transposes (f32 [256][N] -> f16 [N][256]),
// blocks 512+ = f32->f16 cvt for query + inflat.
// ---------------------------------------------------------------------------
__global__ __launch_bounds__(256) void prep_all(
    const float* __restrict__ query, const float* __restrict__ inflat,
    const float* __restrict__ W_val, const float* __restrict__ W_attn,
    const float* __restrict__ W_off, const float* __restrict__ W_out,
    __half* __restrict__ qh, __half* __restrict__ ifh,
    __half* __restrict__ wT_val, __half* __restrict__ wT_ao,
    __half* __restrict__ wT_out, int n4each) {
  int b = blockIdx.x;
  if (b < 512) {
    const float* in;
    __half* out;
    int N;
    if (b < 64) { in = W_val; out = wT_val; N = 256; }
    else if (b < 192) { b -= 64; in = W_attn; out = wT_ao; N = 512; }
    else if (b < 448) { b -= 192; in = W_off; out = wT_ao + (size_t)512 * 256; N = 1024; }
    else { b -= 448; in = W_out; out = wT_out; N = 256; }
    const int nb = N / 32;
    const int n0 = (b % nb) * 32, k0 = (b / nb) * 32;

    __shared__ float t[32][33];
    const int c = threadIdx.x & 31, r = threadIdx.x >> 5;
#pragma unroll
    for (int i = 0; i < 4; ++i)
      t[r + i * 8][c] = in[(size_t)(k0 + r + i * 8) * N + n0 + c];
    __syncthreads();
#pragma unroll
    for (int i = 0; i < 4; ++i)
      out[(size_t)(n0 + r + i * 8) * 256 + k0 + c] = __float2half(t[c][r + i * 8]);
    return;
  }
  int i = (b - 512) * 256 + threadIdx.x;
  const float* in = query;
  __half* out = qh;
  if (i >= n4each) { in = inflat; out = ifh; i -= n4each; }
  const float4 v = reinterpret_cast<const float4*>(in)[i];
  const __half2 p0 = __floats2half2_rn(v.x, v.y);
  const __half2 p1 = __floats2half2_rn(v.z, v.w);
  uint2 pk;
  pk.x = *reinterpret_cast<const uint*>(&p0);
  pk.y = *reinterpret_cast<const uint*>(&p1);
  reinterpret_cast<uint2*>(out)[i] = pk;
}

// ---------------------------------------------------------------------------
// Fused val+attn+off MFMA GEMM: single core, block-uniform pointer selects.
// grid (14, 96): bx 0-1 -> val = ifh @ wT_val -> val_t (head-major TRANS);
// bx 2-13 -> [attn|off] = qh @ wT_ao -> ao_h[LQ][1536].
// 128x128 tile, 4 waves, BK=64, reg-staged swizzled LDS (r12 core),
// XCD-chunked remap (nwg = 1344, %8==0, bijective).
// ---------------------------------------------------------------------------
__global__ __launch_bounds__(256) void gemm_all(
    const __half* __restrict__ qh, const __half* __restrict__ ifh,
    const __half* __restrict__ wT_val, const __half* __restrict__ wT_ao,
    const float* __restrict__ b_val, const float* __restrict__ b_attn,
    const float* __restrict__ b_off,
    __half* __restrict__ val_t, __half* __restrict__ ao_h, int M) {
  __shared__ uint4 As_g[128 * 8];
  __shared__ uint4 Bs_g[128 * 8];

  const int tid = threadIdx.x;

  const int nwg = gridDim.x * gridDim.y;
  int bid = blockIdx.y * gridDim.x + blockIdx.x;
  bid = (bid & 7) * (nwg >> 3) + (bid >> 3);
  const int bx = bid % gridDim.x;
  const int bm = (bid / gridDim.x) * 128;

  const bool isval = (bx < 2);
  const int bn = isval ? bx * 128 : (bx - 2) * 128;
  const __half* __restrict__ A  = isval ? ifh : qh;
  const __half* __restrict__ Bt = isval ? wT_val : wT_ao;
  const float* __restrict__ bias = isval ? b_val : (bn < 512 ? b_attn : b_off);
  const int coff = (!isval && bn >= 512) ? 512 : 0;

  const int wid = tid >> 6, lane = tid & 63;
  const int wr = wid >> 1, wn = wid & 1;
  const int l16 = lane & 15, lhi = lane >> 4;

  floatx4 acc[4][4] = {};

  const int srow = tid >> 1;
  const int sg0 = (tid & 1) * 4;
  const bool arow_ok = (bm + srow) < M;
  const __half* Arow = A + (size_t)(arow_ok ? bm + srow : 0) * 256;
  const __half* Brow = Bt + (size_t)(bn + srow) * 256;

  for (int ks = 0; ks < 4; ++ks) {
    const int k0 = ks * 64;
#pragma unroll
    for (int i = 0; i < 4; ++i) {
      const int g = sg0 + i;
      uint4 av = make_uint4(0, 0, 0, 0);
      if (arow_ok) av = *reinterpret_cast<const uint4*>(Arow + k0 + g * 8);
      As_g[srow * 8 + (g ^ (srow & 7))] = av;
      Bs_g[srow * 8 + (g ^ (srow & 7))] =
          *reinterpret_cast<const uint4*>(Brow + k0 + g * 8);
    }
    __syncthreads();

#pragma unroll
    for (int kk = 0; kk < 2; ++kk) {
      half8 a[4], b[4];
#pragma unroll
      for (int m = 0; m < 4; ++m) {
        const int row = wr * 64 + m * 16 + l16;
        const int g = kk * 4 + lhi;
        union { uint4 u; half8 h; } cv;
        cv.u = As_g[row * 8 + (g ^ (row & 7))];
        a[m] = cv.h;
      }
#pragma unroll
      for (int n = 0; n < 4; ++n) {
        const int row = wn * 64 + n * 16 + l16;
        const int g = kk * 4 + lhi;
        union { uint4 u; half8 h; } cv;
        cv.u = Bs_g[row * 8 + (g ^ (row & 7))];
        b[n] = cv.h;
      }
#pragma unroll
      for (int m = 0; m < 4; ++m)
#pragma unroll
        for (int n = 0; n < 4; ++n)
          acc[m][n] = __builtin_amdgcn_mfma_f32_16x16x32_f16(a[m], b[n], acc[m][n], 0, 0, 0);
    }
    __syncthreads();
  }

#pragma unroll
  for (int m = 0; m < 4; ++m) {
    const int row0 = bm + wr * 64 + m * 16 + lhi * 4;
#pragma unroll
    for (int n = 0; n < 4; ++n) {
      const int col = bn + wn * 64 + n * 16 + l16;
      const float bv = bias[col - coff];
#pragma unroll
      for (int r = 0; r < 4; ++r) {
        const int row = row0 + r;
        if (row < M) {
          const float v = acc[m][n][r] + bv;
          if (isval) {
            val_t[(size_t)(col >> 5) * ((size_t)M * 32) + (size_t)row * 32 + (col & 31)] = __float2half(v);
          } else {
            ao_h[(size_t)row * 1536 + col] = __float2half(v);
          }
        }
      }
    }
  }
}

// ---------------------------------------------------------------------------
// Out-GEMM (r12 core + XCD remap), f32 output.
// ---------------------------------------------------------------------------
__global__ __launch_bounds__(256) void gemm_out(
    const __half* __restrict__ A, const __half* __restrict__ Bt,
    const float* __restrict__ bias, float* __restrict__ C, int M, int N) {
  __shared__ uint4 As_g[128 * 8];
  __shared__ uint4 Bs_g[128 * 8];

  const int tid = threadIdx.x;
  const int nwg = gridDim.x * gridDim.y;
  int bid = blockIdx.y * gridDim.x + blockIdx.x;
  bid = (bid & 7) * (nwg >> 3) + (bid >> 3);
  const int bm = (bid / gridDim.x) * 128, bn = (bid % gridDim.x) * 128;

  const int wid = tid >> 6, lane = tid & 63;
  const int wr = wid >> 1, wn = wid & 1;
  const int l16 = lane & 15, lhi = lane >> 4;

  floatx4 acc[4][4] = {};

  const int srow = tid >> 1;
  const int sg0 = (tid & 1) * 4;
  const bool arow_ok = (bm + srow) < M;
  const __half* Arow = A + (size_t)(arow_ok ? bm + srow : 0) * 256;
  const __half* Brow = Bt + (size_t)(bn + srow) * 256;

  for (int ks = 0; ks < 4; ++ks) {
    const int k0 = ks * 64;
#pragma unroll
    for (int i = 0; i < 4; ++i) {
      const int g = sg0 + i;
      uint4 av = make_uint4(0, 0, 0, 0);
      if (arow_ok) av = *reinterpret_cast<const uint4*>(Arow + k0 + g * 8);
      As_g[srow * 8 + (g ^ (srow & 7))] = av;
      Bs_g[srow * 8 + (g ^ (srow & 7))] =
          *reinterpret_cast<const uint4*>(Brow + k0 + g * 8);
    }
    __syncthreads();

#pragma unroll
    for (int kk = 0; kk < 2; ++kk) {
      half8 a[4], b[4];
#pragma unroll
      for (int m = 0; m < 4; ++m) {
        const int row = wr * 64 + m * 16 + l16;
        const int g = kk * 4 + lhi;
        union { uint4 u; half8 h; } cv;
        cv.u = As_g[row * 8 + (g ^ (row & 7))];
        a[m] = cv.h;
      }
#pragma unroll
      for (int n = 0; n < 4; ++n) {
        const int row = wn * 64 + n * 16 + l16;
        const int g = kk * 4 + lhi;
        union { uint4 u; half8 h; } cv;
        cv.u = Bs_g[row * 8 + (g ^ (row & 7))];
        b[n] = cv.h;
      }
#pragma unroll
      for (int m = 0; m < 4; ++m)
#pragma unroll
        for (int n = 0; n < 4; ++n)
          acc[m][n] = __builtin_amdgcn_mfma_f32_16x16x32_f16(a[m], b[n], acc[m][n], 0, 0, 0);
    }
    __syncthreads();
  }

#pragma unroll
  for (int m = 0; m < 4; ++m) {
    const int row0 = bm + wr * 64 + m * 16 + lhi * 4;
#pragma unroll
    for (int n = 0; n < 4; ++n) {
      const int col = bn + wn * 64 + n * 16 + l16;
      const float bv = bias[col];
#pragma unroll
      for (int r = 0; r < 4; ++r) {
        const int row = row0 + r;
        if (row < M) C[(size_t)row * N + col] = acc[m][n][r] + bv;
      }
    }
  }
}

// ---------------------------------------------------------------------------
// packed record helper
// ---------------------------------------------------------------------------
__device__ inline uint pack_wr(float w, uint row) {
  const __half hw = __float2half(w);
  return ((uint)__half_as_ushort(hw) << 16) | row;   // row < 12240 < 2^16
}

// ---------------------------------------------------------------------------
// Fused softmax + location + deformable bilinear sampling.
// value = head-major val_t[8][LQ][32]; logits/off from combined ao (stride
// 1536). Phase-2 weight broadcast via v_pk_fma_f16 op_sel:[1,0,0].
// ---------------------------------------------------------------------------
__global__ __launch_bounds__(256, 8) void sample_kernel(
    const __half* __restrict__ value,     // val_t [8][LQ][32] f16
    const __half* __restrict__ ao,        // (LQ, 1536): 512 logits | 1024 off
    const float* __restrict__ tempoff,    // (LQ, 4, 4, 2) f32
    const float* __restrict__ refpts,     // (LQ, 4, 2) f32
    __half* __restrict__ msout) {         // (LQ, 256) f16
  const int q0 = blockIdx.x * 2;
  const int tid = threadIdx.x;

  __shared__ __align__(16) uint spk[4096];   // 16 KB packed records
  float* slog = reinterpret_cast<float*>(spk);  // overlay: logits f32[1024]
  __shared__ float sm_m[16], sm_si[16];

  // ---- (a) load logits (2 queries x 512) ----
#pragma unroll
  for (int k = 0; k < 4; ++k) {
    const int s = tid + k * 256;
    slog[s] = __half2float(ao[(size_t)(q0 + (s >> 9)) * 1536 + (s & 511)]);
  }
  __syncthreads();

  // ---- (b) per-(query,head) softmax stats: 16 groups x 16 threads ----
  {
    const int g = tid >> 4;
    const int j = tid & 15;
    const float* e = &slog[g * 64];
    float m = fmaxf(fmaxf(e[j], e[j + 16]), fmaxf(e[j + 32], e[j + 48]));
#pragma unroll
    for (int mask = 8; mask >= 1; mask >>= 1) m = fmaxf(m, __shfl_xor(m, mask));
    float s = __expf(e[j] - m) + __expf(e[j + 16] - m) +
              __expf(e[j + 32] - m) + __expf(e[j + 48] - m);
#pragma unroll
    for (int mask = 8; mask >= 1; mask >>= 1) s += __shfl_xor(s, mask);
    if (j == 0) { sm_m[g] = m; sm_si[g] = 1.0f / s; }
  }
  __syncthreads();

  // ---- (c) per-(sample,corner) records -> registers ----
  const float HWF[4] = {2304.f, 576.f, 144.f, 36.f};
  const float RHW[4] = {1.f / 2304.f, 1.f / 576.f, 1.f / 144.f, 1.f / 36.f};
  const int   S0[4]  = {0, 9216, 11520, 12096};
  const int   HWI[4] = {2304, 576, 144, 36};

  uint4 rec[4];
  int   ridx[4];
  const int h1   = tid & 7;
  const int smid = (tid >> 3) & 7;
  const int shi  = (tid >> 6) & 3;

#pragma unroll
  for (int k = 0; k < 4; ++k) {
    const int qi = k & 1;
    const int s  = smid | (shi << 3) | ((k >> 1) << 5);  // sample id 0..63
    const int i  = h1 * 64 + s;
    const int l  = s >> 4;
    const int f  = (s >> 2) & 3;
    const size_t q = (size_t)(q0 + qi);
    const int g = (qi << 3) | h1;

    const float w = __expf(slog[(qi << 9) + i] - sm_m[g]) * sm_si[g];

    const float2 o  = __half22float2(*reinterpret_cast<const __half2*>(&ao[q * 1536 + 512 + i * 2]));
    const float2 to = *reinterpret_cast<const float2*>(&tempoff[q * 32 + (l * 4 + f) * 2]);
    const float2 rp = *reinterpret_cast<const float2*>(&refpts[q * 8 + l * 2]);

    const float hw = HWF[l];
    const float x = (to.x + o.x * 0.25f + rp.x) * 4.0f - 0.5f;
    const float y = (to.y + o.y * RHW[l] + rp.y) * hw - 0.5f;

    const float x0f = floorf(x), y0f = floorf(y);
    const float fx = x - x0f, fy = y - y0f;
    const int x0 = (int)x0f, y0 = (int)y0f;
    const int hl = HWI[l];

    const bool xv0 = (x0 >= 0) && (x0 < 4);
    const bool xv1 = (x0 >= -1) && (x0 < 3);
    const bool yv0 = (y0 >= 0) && (y0 < hl);
    const bool yv1 = (y0 >= -1) && (y0 < hl - 1);
    const int xc0 = min(max(x0, 0), 3);
    const int xc1 = min(max(x0 + 1, 0), 3);
    const int yc0 = min(max(y0, 0), hl - 1);
    const int yc1 = min(max(y0 + 1, 0), hl - 1);

    const float w00 = (xv0 && yv0) ? w * (1.f - fx) * (1.f - fy) : 0.f;
    const float w01 = (xv1 && yv0) ? w * fx * (1.f - fy) : 0.f;
    const float w10 = (xv0 && yv1) ? w * (1.f - fx) * fy : 0.f;
    const float w11 = (xv1 && yv1) ? w * fx * fy : 0.f;

    const int base = S0[l];
    rec[k] = make_uint4(pack_wr(w00, (uint)(base + yc0 * 4 + xc0)),
                        pack_wr(w01, (uint)(base + yc0 * 4 + xc1)),
                        pack_wr(w10, (uint)(base + yc1 * 4 + xc0)),
                        pack_wr(w11, (uint)(base + yc1 * 4 + xc1)));
    ridx[k] = (qi << 9) | (s << 3) | h1;   // uint4-granule index
  }
  __syncthreads();

  // ---- (d) write records (consecutive granules per wave: conflict-free) ----
  uint4* spk4 = reinterpret_cast<uint4*>(spk);
#pragma unroll
  for (int k = 0; k < 4; ++k) spk4[ridx[k]] = rec[k];
  __syncthreads();

  // ---- phase 2: gather + packed FMA ----
  const int qi = tid >> 7;          // 0..1
  const int h  = (tid >> 4) & 7;    // 0..7
  const int c  = (tid >> 2) & 3;    // corner
  const int d  = tid & 3;           // dim quarter

  const uint* __restrict__ sp = spk + ((qi << 11) | (h << 2) | c);
  const char* __restrict__ vbase =
      (const char*)value + (size_t)h * LQ * 64 + d * 16;

  float f0 = 0.f, f1 = 0.f, f2 = 0.f, f3 = 0.f;
  float f4 = 0.f, f5 = 0.f, f6 = 0.f, f7 = 0.f;

#pragma unroll
  for (int l = 0; l < 4; ++l) {
    uint a0 = 0u, a1 = 0u, a2 = 0u, a3 = 0u;
#pragma unroll
    for (int t = 0; t < 16; ++t) {
      const uint pk = sp[(l * 16 + t) << 5];           // ds_read_b32 imm offs
      const uint4 v = *reinterpret_cast<const uint4*>(vbase + ((pk & 0xFFFFu) << 6));
      asm("v_pk_fma_f16 %0, %4, %5, %0 op_sel:[1,0,0]\n\t"
          "v_pk_fma_f16 %1, %4, %6, %1 op_sel:[1,0,0]\n\t"
          "v_pk_fma_f16 %2, %4, %7, %2 op_sel:[1,0,0]\n\t"
          "v_pk_fma_f16 %3, %4, %8, %3 op_sel:[1,0,0]"
          : "+v"(a0), "+v"(a1), "+v"(a2), "+v"(a3)
          : "v"(pk), "v"(v.x), "v"(v.y), "v"(v.z), "v"(v.w));
    }
    const float2 p0 = __half22float2(*reinterpret_cast<const __half2*>(&a0));
    const float2 p1 = __half22float2(*reinterpret_cast<const __half2*>(&a1));
    const float2 p2 = __half22float2(*reinterpret_cast<const __half2*>(&a2));
    const float2 p3 = __half22float2(*reinterpret_cast<const __half2*>(&a3));
    f0 += p0.x; f1 += p0.y; f2 += p1.x; f3 += p1.y;
    f4 += p2.x; f5 += p2.y; f6 += p3.x; f7 += p3.y;
  }

#pragma unroll
  for (int mask = 4; mask <= 8; mask <<= 1) {
    f0 += __shfl_xor(f0, mask); f1 += __shfl_xor(f1, mask);
    f2 += __shfl_xor(f2, mask); f3 += __shfl_xor(f3, mask);
    f4 += __shfl_xor(f4, mask); f5 += __shfl_xor(f5, mask);
    f6 += __shfl_xor(f6, mask); f7 += __shfl_xor(f7, mask);
  }

  if (c == 0) {
    const __half2 o0 = __floats2half2_rn(f0, f1);
    const __half2 o1 = __floats2half2_rn(f2, f3);
    const __half2 o2 = __floats2half2_rn(f4, f5);
    const __half2 o3 = __floats2half2_rn(f6, f7);
    uint4 st;
    st.x = *reinterpret_cast<const uint*>(&o0);
    st.y = *reinterpret_cast<const uint*>(&o1);
    st.z = *reinterpret_cast<const uint*>(&o2);
    st.w = *reinterpret_cast<const uint*>(&o3);
    *reinterpret_cast<uint4*>(&msout[(size_t)(q0 + qi) * 256 + h * 32 + d * 8]) = st;
  }
}

// ---------------------------------------------------------------------------
extern "C" void kernel_launch(void* const* d_in, const int* in_sizes, int n_in,
                              void* d_out, int out_size, void* d_ws, size_t ws_size,
                              hipStream_t stream) {
  const float* query   = (const float*)d_in[0];
  const float* refpts  = (const float*)d_in[1];
  const float* tempoff = (const float*)d_in[2];
  const float* inflat  = (const float*)d_in[3];
  const float* W_off  = (const float*)d_in[6];
  const float* b_off  = (const float*)d_in[7];
  const float* W_attn = (const float*)d_in[8];
  const float* b_attn = (const float*)d_in[9];
  const float* W_val  = (const float*)d_in[10];
  const float* b_val  = (const float*)d_in[11];
  const float* W_out  = (const float*)d_in[12];
  const float* b_out  = (const float*)d_in[13];

  char* ws = (char*)d_ws;
  const size_t szQ = (size_t)LQ * 256 * 2;
  __half* qh     = (__half*)ws;                 ws += szQ;
  __half* ifh    = (__half*)ws;                 ws += szQ;
  __half* wT_val = (__half*)ws;                 ws += (size_t)256 * 256 * 2;
  __half* wT_ao  = (__half*)ws;                 ws += (size_t)1536 * 256 * 2;
  __half* wT_out = (__half*)ws;                 ws += (size_t)256 * 256 * 2;
  __half* val_t  = (__half*)ws;                 ws += szQ;
  __half* ao_h   = (__half*)ws;                 ws += (size_t)LQ * 1536 * 2;
  __half* ms_h   = (__half*)ws;                 ws += szQ;

  const dim3 blk(256);
  const int n4each = LQ * 256 / 4;  // 783360

  prep_all<<<dim3(512 + 2 * n4each / 256), blk, 0, stream>>>(
      query, inflat, W_val, W_attn, W_off, W_out,
      qh, ifh, wT_val, wT_ao, wT_out, n4each);

  const int gm = (LQ + 127) / 128;  // 96
  gemm_all<<<dim3(14, gm), blk, 0, stream>>>(qh, ifh, wT_val, wT_ao,
                                             b_val, b_attn, b_off,
                                             val_t, ao_h, LQ);

  sample_kernel<<<dim3(LQ / 2), blk, 0, stream>>>(val_t, ao_h, tempoff, refpts, ms_h);

  gemm_out<<<dim3(2, gm), blk, 0, stream>>>(ms_h, wT_out, b_out, (float*)d_out, LQ, 256);
}